// Round 6
// baseline (2239.437 us; speedup 1.0000x reference)
//
#include <hip/hip_runtime.h>
#include <hip/hip_bf16.h>

typedef __bf16 bf16x4_v __attribute__((ext_vector_type(4)));
typedef __bf16 bf16x8_v __attribute__((ext_vector_type(8)));
typedef float  f32x4_v  __attribute__((ext_vector_type(4)));

static constexpr int kH = 1024;
static constexpr int kD = 2048;   // 2H
static constexpr int kB = 64;
static constexpr int kS = 2048;
static constexpr int kM = kB * kS;  // 131072 rows of the big GEMM

__device__ __forceinline__ void load_lds16(const void* g, void* l) {
  __builtin_amdgcn_global_load_lds(
      (const __attribute__((address_space(1))) unsigned int*)g,
      (__attribute__((address_space(3))) unsigned int*)l, 16, 0, 0);
}

__device__ __forceinline__ float fast_tanh(float x) {
  float e = __expf(2.0f * x);
  return 1.0f - 2.0f * __builtin_amdgcn_rcpf(e + 1.0f);
}

// ---- W_h fp32 -> bf16, re-tiled for swizzled global_load_lds staging -------
// Tiles [kH/8][kD/64], each 8x64 bf16 = 1024B; 16B chunk l holds logical
// chunk l ^ (l>>3) so linear gload_lds writes match the (row&7)<<4 read swizzle.
__global__ __launch_bounds__(256) void conv_wh_kernel(const float* __restrict__ W,
                                                      __bf16* __restrict__ out) {
  int g = blockIdx.x * 256 + threadIdx.x;   // 262144 chunks of 16B
  int tile = g >> 6, l = g & 63;
  int sc = l ^ (l >> 3);
  int h = (tile >> 5) * 8 + (sc >> 3);
  int k = (tile & 31) * 64 + (sc & 7) * 8;
  const float4* s = reinterpret_cast<const float4*>(W + (size_t)h * kD + k);
  float4 v0 = s[0], v1 = s[1];
  bf16x8_v o = {(__bf16)v0.x, (__bf16)v0.y, (__bf16)v0.z, (__bf16)v0.w,
                (__bf16)v1.x, (__bf16)v1.y, (__bf16)v1.z, (__bf16)v1.w};
  reinterpret_cast<bf16x8_v*>(out)[g] = o;
}

// ------------- biasBH[b][h] = s_t[b] . W_s[h] + b_s[h] + b_h[h] -------------
__global__ __launch_bounds__(256) void prep_bias_kernel(
    const float* __restrict__ s_t, const float* __restrict__ W_s,
    const float* __restrict__ b_s, const float* __restrict__ b_h,
    float* __restrict__ biasBH) {
  int wave = blockIdx.x * 4 + (threadIdx.x >> 6);  // 65536 outputs
  int lane = threadIdx.x & 63;
  int b = wave >> 10, h = wave & 1023;
  const float4* sp = reinterpret_cast<const float4*>(s_t + (size_t)b * kD);
  const float4* wp = reinterpret_cast<const float4*>(W_s + (size_t)h * kD);
  float acc = 0.f;
  for (int i = lane; i < kD / 4; i += 64) {
    float4 a = sp[i], w = wp[i];
    acc += a.x * w.x + a.y * w.y + a.z * w.z + a.w * w.w;
  }
  for (int m = 1; m < 64; m <<= 1) acc += __shfl_xor(acc, m);
  if (lane == 0) biasBH[wave] = acc + b_s[h] + b_h[h];
}

// ---------------- big GEMM + fused tanh/v_a epilogue -> E -------------------
// 128x128 tile, BK=64, 4 waves (2x2).
// A: loaded DIRECTLY global->VGPR in MFMA fragment layout (no LDS round-trip),
//    fp32->bf16 converted in-register; issued 1 step ahead.
// B: global_load_lds 2 steps ahead into 3 LDS buffers (48 KB total).
// Barriers are raw s_barrier + lgkmcnt(0); vmcnt never drained mid-loop --
// the av-convert's implicit vmcnt wait transitively covers older B gloads.
__global__ __launch_bounds__(256, 2) void gemm_score_kernel(
    const float* __restrict__ h_i,      // (kM, kD) fp32
    const __bf16* __restrict__ Wh,      // tiled bf16 (see conv_wh_kernel)
    const float* __restrict__ biasBH,   // (kB, kH)
    const float* __restrict__ coverage, // (kB, kS)
    const float* __restrict__ Wc,       // (kH)
    const float* __restrict__ va,       // (kH)
    float* __restrict__ E) {            // (kB, kS), pre-zeroed
  const int bid = blockIdx.x;
  const int xcd = bid & 7;
  const int slot = bid >> 3;
  const int n0 = (slot & 7) * 128;
  const int m0 = (xcd * 128 + (slot >> 3)) * 128;

  const int tid = threadIdx.x;
  const int lane = tid & 63;
  const int wid = tid >> 6;        // 0..3
  const int wm = wid >> 1, wn = wid & 1;

  __shared__ __bf16 Bs[3][128 * 64];   // 48 KB
  char* Bsb = (char*)Bs;

  f32x4_v acc[4][4];
#pragma unroll
  for (int m = 0; m < 4; ++m)
#pragma unroll
    for (int n = 0; n < 4; ++n) acc[m][n] = {0.f, 0.f, 0.f, 0.f};

  const int rB = wn * 64 + (lane & 15);
  const int khalf = (lane >> 4) * 16;      // byte offset of k-group in 32-col half
  const int swz = (lane & 7) << 4;         // row-swizzle term for B reads

  // A direct-fragment base: row = m0 + wm*64 + (lane&15), k-off = (lane>>4)*8
  const float* Agb = h_i + (size_t)(m0 + wm * 64 + (lane & 15)) * kD + ((lane >> 4) * 8);
  const __bf16* Btb = Wh + ((size_t)(((n0 + wid * 32) >> 3) * 32)) * 512 + (size_t)lane * 8;

  float4  av[16];    // fp32 in-flight A frags: [m][ks][half]
  bf16x8_v af[8];    // converted bf16 A frags: [m][ks]

  // ---- prologue: issue B(0)->buf0, B(1)->buf1, A(0)->av; wait-all; barrier
  {
#pragma unroll
    for (int p = 0; p < 4; ++p)
      load_lds16(Btb + (size_t)p * (32 * 512), Bsb + (wid * 32 + p * 8) * 128);
#pragma unroll
    for (int p = 0; p < 4; ++p)
      load_lds16(Btb + 512 + (size_t)p * (32 * 512), Bsb + 16384 + (wid * 32 + p * 8) * 128);
    __builtin_amdgcn_sched_barrier(0);
#pragma unroll
    for (int m = 0; m < 4; ++m)
#pragma unroll
      for (int ks = 0; ks < 2; ++ks)
#pragma unroll
        for (int h = 0; h < 2; ++h)
          av[m * 4 + ks * 2 + h] = *reinterpret_cast<const float4*>(
              Agb + (size_t)(m * 16) * kD + ks * 32 + h * 4);
    asm volatile("s_waitcnt vmcnt(0) lgkmcnt(0)" ::: "memory");
    __builtin_amdgcn_s_barrier();
    asm volatile("" ::: "memory");
  }

  for (int t = 0; t < 32; ++t) {
    // ---- 1. convert av (=A(t)) -> af; implicit vmcnt wait covers B(t+1) too
#pragma unroll
    for (int m = 0; m < 4; ++m)
#pragma unroll
      for (int ks = 0; ks < 2; ++ks) {
        float4 lo = av[m * 4 + ks * 2], hi = av[m * 4 + ks * 2 + 1];
        af[m * 2 + ks] = bf16x8_v{(__bf16)lo.x, (__bf16)lo.y, (__bf16)lo.z, (__bf16)lo.w,
                                  (__bf16)hi.x, (__bf16)hi.y, (__bf16)hi.z, (__bf16)hi.w};
      }
    __builtin_amdgcn_sched_barrier(0);

    // ---- 2. issue B(t+2) gload_lds
    if (t + 2 < 32) {
      char* Bn = Bsb + ((t + 2) % 3) * 16384;
      const __bf16* tb2 = Btb + (size_t)(t + 2) * 512;
#pragma unroll
      for (int p = 0; p < 4; ++p)
        load_lds16(tb2 + (size_t)p * (32 * 512), Bn + (wid * 32 + p * 8) * 128);
    }
    // ---- 3. issue A(t+1) global loads into av
    if (t + 1 < 32) {
      const float* Ag = Agb + (size_t)(t + 1) * 64;
#pragma unroll
      for (int m = 0; m < 4; ++m)
#pragma unroll
        for (int ks = 0; ks < 2; ++ks)
#pragma unroll
          for (int h = 0; h < 2; ++h)
            av[m * 4 + ks * 2 + h] = *reinterpret_cast<const float4*>(
                Ag + (size_t)(m * 16) * kD + ks * 32 + h * 4);
    }
    __builtin_amdgcn_sched_barrier(0);

    // ---- 4. MFMA phase on B buf t%3 + af
    {
      char* Bb = Bsb + (t % 3) * 16384;
      __builtin_amdgcn_s_setprio(1);
#pragma unroll
      for (int ks = 0; ks < 2; ++ks) {
        const int cb = (ks * 64 + khalf) ^ swz;
        bf16x8_v b[4];
#pragma unroll
        for (int n = 0; n < 4; ++n)
          b[n] = *reinterpret_cast<const bf16x8_v*>(Bb + (rB + n * 16) * 128 + cb);
#pragma unroll
        for (int m = 0; m < 4; ++m)
#pragma unroll
          for (int n = 0; n < 4; ++n)
            acc[m][n] = __builtin_amdgcn_mfma_f32_16x16x32_bf16(af[m * 2 + ks], b[n],
                                                                acc[m][n], 0, 0, 0);
      }
      __builtin_amdgcn_s_setprio(0);
    }

    // ---- 5. end-of-step barrier (LDS only; vmcnt stays in flight)
    asm volatile("s_waitcnt lgkmcnt(0)" ::: "memory");
    __builtin_amdgcn_s_barrier();
    asm volatile("" ::: "memory");
  }

  // ---- epilogue: z = acc + bias + cov*Wc; E_partial = sum_h tanh(z)*va[h]
  const int bb = m0 >> 11;            // batch (uniform per block)
  const int colg = lane & 15;
  const int rowg = lane >> 4;         // 0..3
  float bias_v[4], wc_v[4], va_v[4];
#pragma unroll
  for (int n = 0; n < 4; ++n) {
    int h = n0 + wn * 64 + n * 16 + colg;
    bias_v[n] = biasBH[bb * kH + h];
    wc_v[n] = Wc[h];
    va_v[n] = va[h];
  }
  const int s_tile = (m0 & (kS - 1));
  float rowsum[4][4];
#pragma unroll
  for (int m = 0; m < 4; ++m)
#pragma unroll
    for (int j = 0; j < 4; ++j) rowsum[m][j] = 0.f;

#pragma unroll
  for (int m = 0; m < 4; ++m) {
    int sbase = s_tile + wm * 64 + m * 16 + rowg * 4;
    float cov[4];
#pragma unroll
    for (int j = 0; j < 4; ++j) cov[j] = coverage[bb * kS + sbase + j];
#pragma unroll
    for (int n = 0; n < 4; ++n) {
#pragma unroll
      for (int j = 0; j < 4; ++j) {
        float z = acc[m][n][j] + bias_v[n] + cov[j] * wc_v[n];
        rowsum[m][j] += fast_tanh(z) * va_v[n];
      }
    }
  }
#pragma unroll
  for (int m = 0; m < 4; ++m) {
#pragma unroll
    for (int j = 0; j < 4; ++j) {
      float v = rowsum[m][j];
      v += __shfl_xor(v, 1);
      v += __shfl_xor(v, 2);
      v += __shfl_xor(v, 4);
      v += __shfl_xor(v, 8);
      if (colg == 0) {
        int s = s_tile + wm * 64 + m * 16 + rowg * 4 + j;
        atomicAdd(&E[bb * kS + s], v);
      }
    }
  }
}

// ---------------- softmax over S per (b); A and new_cov ---------------------
__global__ __launch_bounds__(256) void softmax_kernel(
    const float* __restrict__ E, const float* __restrict__ coverage,
    float* __restrict__ A, float* __restrict__ newcov) {
  int b = blockIdx.x;
  int tid = threadIdx.x;
  int wid = tid >> 6, lane = tid & 63;
  __shared__ float wred[4];
  float ev[8];
  float mx = -INFINITY;
#pragma unroll
  for (int i = 0; i < 8; ++i) {
    ev[i] = E[b * kS + tid + i * 256];
    mx = fmaxf(mx, ev[i]);
  }
  for (int m = 1; m < 64; m <<= 1) mx = fmaxf(mx, __shfl_xor(mx, m));
  if (lane == 0) wred[wid] = mx;
  __syncthreads();
  mx = fmaxf(fmaxf(wred[0], wred[1]), fmaxf(wred[2], wred[3]));
  __syncthreads();
  float sum = 0.f;
#pragma unroll
  for (int i = 0; i < 8; ++i) {
    ev[i] = __expf(ev[i] - mx);
    sum += ev[i];
  }
  for (int m = 1; m < 64; m <<= 1) sum += __shfl_xor(sum, m);
  if (lane == 0) wred[wid] = sum;
  __syncthreads();
  sum = wred[0] + wred[1] + wred[2] + wred[3];
  float inv = 1.f / sum;
#pragma unroll
  for (int i = 0; i < 8; ++i) {
    int s = tid + i * 256;
    float a = ev[i] * inv;
    A[b * kS + s] = a;
    newcov[b * kS + s] = coverage[b * kS + s] + a;
  }
}

// ---------------- context C[b] = sum_s A[b,s] * h_i[b,s,:] ------------------
__global__ __launch_bounds__(256) void context_kernel(
    const float* __restrict__ h_i, const float* __restrict__ A,
    float* __restrict__ C) {
  int b = blockIdx.x;
  int d = blockIdx.y * 1024 + threadIdx.x * 4;
  int s0 = blockIdx.z * 256;
  const float* hp = h_i + ((size_t)b * kS + s0) * kD + d;
  const float* ap = A + b * kS + s0;
  float4 acc = {0.f, 0.f, 0.f, 0.f};
  for (int s = 0; s < 256; ++s) {
    float a = ap[s];
    float4 v = *reinterpret_cast<const float4*>(hp + (size_t)s * kD);
    acc.x += a * v.x;
    acc.y += a * v.y;
    acc.z += a * v.z;
    acc.w += a * v.w;
  }
  atomicAdd(&C[b * kD + d + 0], acc.x);
  atomicAdd(&C[b * kD + d + 1], acc.y);
  atomicAdd(&C[b * kD + d + 2], acc.z);
  atomicAdd(&C[b * kD + d + 3], acc.w);
}

extern "C" void kernel_launch(void* const* d_in, const int* in_sizes, int n_in,
                              void* d_out, int out_size, void* d_ws, size_t ws_size,
                              hipStream_t stream) {
  const float* s_t      = (const float*)d_in[0];
  const float* h_i      = (const float*)d_in[1];
  const float* coverage = (const float*)d_in[2];
  const float* W_h      = (const float*)d_in[3];
  const float* b_h      = (const float*)d_in[4];
  const float* W_s      = (const float*)d_in[5];
  const float* b_s      = (const float*)d_in[6];
  const float* W_c      = (const float*)d_in[7];
  const float* v_a      = (const float*)d_in[8];
  // d_in[9] = b_a: softmax-shift-invariant and E is not an output -> unused.

  float* out = (float*)d_out;
  float* C      = out;                 // (kB, kD)
  float* A      = out + kB * kD;       // (kB, kS)
  float* newcov = A + kB * kS;         // (kB, kS)

  char* ws = (char*)d_ws;
  __bf16* Wh_bf  = (__bf16*)ws;                               // 4 MB (tiled)
  float* biasBH  = (float*)(ws + (4u << 20));                 // 256 KB
  float* E       = (float*)(ws + (4u << 20) + (256u << 10));  // 512 KB

  hipMemsetAsync(E, 0, (size_t)kB * kS * sizeof(float), stream);
  hipMemsetAsync(C, 0, (size_t)kB * kD * sizeof(float), stream);

  conv_wh_kernel<<<(kH * kD / 8) / 256, 256, 0, stream>>>(W_h, Wh_bf);
  prep_bias_kernel<<<(kB * kH) / 4, 256, 0, stream>>>(s_t, W_s, b_s, b_h, biasBH);

  gemm_score_kernel<<<8192, 256, 0, stream>>>(h_i, Wh_bf, biasBH, coverage, W_c, v_a, E);

  softmax_kernel<<<kB, 256, 0, stream>>>(E, coverage, A, newcov);

  dim3 gc(kB, kD / 1024, kS / 256);
  context_kernel<<<gc, 256, 0, stream>>>(h_i, A, C);
}

// Round 7
// 1405.292 us; speedup vs baseline: 1.5936x; 1.5936x over previous
//
#include <hip/hip_runtime.h>
#include <hip/hip_bf16.h>

typedef __bf16 bf16x4_v __attribute__((ext_vector_type(4)));
typedef __bf16 bf16x8_v __attribute__((ext_vector_type(8)));
typedef float  f32x4_v  __attribute__((ext_vector_type(4)));

static constexpr int kH = 1024;
static constexpr int kD = 2048;   // 2H
static constexpr int kB = 64;
static constexpr int kS = 2048;
static constexpr int kM = kB * kS;  // 131072 rows of the big GEMM

__device__ __forceinline__ void load_lds16(const void* g, void* l) {
  __builtin_amdgcn_global_load_lds(
      (const __attribute__((address_space(1))) unsigned int*)g,
      (__attribute__((address_space(3))) unsigned int*)l, 16, 0, 0);
}

__device__ __forceinline__ float fast_tanh(float x) {
  float e = __expf(2.0f * x);
  return 1.0f - 2.0f * __builtin_amdgcn_rcpf(e + 1.0f);
}

// ---- W_h fp32 -> bf16, tiled for BK=32 gload_lds staging -------------------
// Layout: [ntile(8)][t(64)][512 chunks of 16B]. Chunk q: row = q>>2 (0..127),
// slot = q&3. Chunk holds logical k-chunk c = (slot - (row>>1)) & 3, i.e.
// W_h[ntile*128+row][t*32 + c*8 .. +8]. The read side uses
// slot = (j + (row>>1)) & 3, giving bank-uniform ds_read_b128.
__global__ __launch_bounds__(256) void conv_wh_kernel(const float* __restrict__ W,
                                                      __bf16* __restrict__ out) {
  int g = blockIdx.x * 256 + threadIdx.x;   // 262144 chunks of 16B
  int q = g & 511;
  int t = (g >> 9) & 63;
  int ntile = g >> 15;
  int row = q >> 2, slot = q & 3;
  int c = (slot - (row >> 1)) & 3;
  const float* s = W + (size_t)(ntile * 128 + row) * kD + t * 32 + c * 8;
  float4 v0 = reinterpret_cast<const float4*>(s)[0];
  float4 v1 = reinterpret_cast<const float4*>(s)[1];
  bf16x8_v o = {(__bf16)v0.x, (__bf16)v0.y, (__bf16)v0.z, (__bf16)v0.w,
                (__bf16)v1.x, (__bf16)v1.y, (__bf16)v1.z, (__bf16)v1.w};
  reinterpret_cast<bf16x8_v*>(out)[g] = o;
}

// ------------- biasBH[b][h] = s_t[b] . W_s[h] + b_s[h] + b_h[h] -------------
__global__ __launch_bounds__(256) void prep_bias_kernel(
    const float* __restrict__ s_t, const float* __restrict__ W_s,
    const float* __restrict__ b_s, const float* __restrict__ b_h,
    float* __restrict__ biasBH) {
  int wave = blockIdx.x * 4 + (threadIdx.x >> 6);  // 65536 outputs
  int lane = threadIdx.x & 63;
  int b = wave >> 10, h = wave & 1023;
  const float4* sp = reinterpret_cast<const float4*>(s_t + (size_t)b * kD);
  const float4* wp = reinterpret_cast<const float4*>(W_s + (size_t)h * kD);
  float acc = 0.f;
  for (int i = lane; i < kD / 4; i += 64) {
    float4 a = sp[i], w = wp[i];
    acc += a.x * w.x + a.y * w.y + a.z * w.z + a.w * w.w;
  }
  for (int m = 1; m < 64; m <<= 1) acc += __shfl_xor(acc, m);
  if (lane == 0) biasBH[wave] = acc + b_s[h] + b_h[h];
}

// ---------------- big GEMM + fused tanh/v_a epilogue -> E -------------------
// 128x128 tile, BK=32 (64 K-steps), 4 waves (2x2).
// BOTH operands staged with global_load_lds into 3-deep buffers:
//   A: fp32 128x32 (16 KB/buf), per-lane pre-swizzled global source so the
//      linear LDS image equals the c^(row&7) 16B-chunk swizzle.
//   B: bf16 pre-tiled+rotated by conv_wh (8 KB/buf).
// fp32->bf16 conversion happens AFTER the fragment ds_read, in registers.
// Counted vmcnt(12/6/0) -- never a full drain in the main loop.
__global__ __launch_bounds__(256, 2) void gemm_score_kernel(
    const float* __restrict__ h_i,      // (kM, kD) fp32
    const __bf16* __restrict__ Wh,      // tiled bf16 (see conv_wh_kernel)
    const float* __restrict__ biasBH,   // (kB, kH)
    const float* __restrict__ coverage, // (kB, kS)
    const float* __restrict__ Wc,       // (kH)
    const float* __restrict__ va,       // (kH)
    float* __restrict__ E) {            // (kB, kS), pre-zeroed
  const int bid = blockIdx.x;
  const int xcd = bid & 7;
  const int slot = bid >> 3;
  const int ntile = slot & 7;
  const int n0 = ntile * 128;
  const int m0 = (xcd * 128 + (slot >> 3)) * 128;

  const int tid = threadIdx.x;
  const int lane = tid & 63;
  const int wid = tid >> 6;        // 0..3
  const int wm = wid >> 1, wn = wid & 1;

  __shared__ float  Al[3][128 * 32];   // 48 KB
  __shared__ __bf16 Bl[3][128 * 32];   // 24 KB
  char* Ab0 = (char*)Al;
  char* Bb0 = (char*)Bl;

  f32x4_v acc[4][4];
#pragma unroll
  for (int m = 0; m < 4; ++m)
#pragma unroll
    for (int n = 0; n < 4; ++n) acc[m][n] = {0.f, 0.f, 0.f, 0.f};

  const int rA = wm * 64 + (lane & 15);
  const int rB = wn * 64 + (lane & 15);
  const int j = lane >> 4;             // k-group 0..3

  const float* Ag = h_i + (size_t)m0 * kD;
  const __bf16* Bg = Wh + (size_t)ntile * (64 * 512 * 8);

  // per-thread staging geometry
  const int aq0 = tid;                 // A chunks: aq0 + k*256, k<4
  // row = q>>3, c = q&7 ; src chunk = c ^ (row&7)

#define STAGE(T)                                                                \
  do {                                                                          \
    char* Ad = Ab0 + ((T) % 3) * 16384;                                         \
    char* Bd = Bb0 + ((T) % 3) * 8192;                                          \
    const float* As_ = Ag + (T) * 32;                                           \
    _Pragma("unroll")                                                           \
    for (int k = 0; k < 4; ++k) {                                               \
      int q = aq0 + k * 256;                                                    \
      int row = q >> 3, c = q & 7;                                              \
      load_lds16(As_ + (size_t)row * kD + ((c ^ (row & 7)) << 2), Ad + q * 16); \
    }                                                                           \
    const __bf16* Bs_ = Bg + (size_t)(T) * 4096;                                \
    _Pragma("unroll")                                                           \
    for (int k = 0; k < 2; ++k) {                                               \
      int q = tid + k * 256;                                                    \
      load_lds16(Bs_ + q * 8, Bd + q * 16);                                     \
    }                                                                           \
  } while (0)

#define STEP_BODY(T)                                                            \
  do {                                                                          \
    __builtin_amdgcn_s_barrier();                                               \
    __builtin_amdgcn_sched_barrier(0);                                          \
    char* Ab = Ab0 + ((T) % 3) * 16384;                                         \
    char* Bb = Bb0 + ((T) % 3) * 8192;                                          \
    bf16x8_v af[4], bf[4];                                                      \
    _Pragma("unroll")                                                           \
    for (int m = 0; m < 4; ++m) {                                               \
      int row = rA + m * 16;                                                    \
      const char* base = Ab + row * 128;                                        \
      f32x4_v lo = *reinterpret_cast<const f32x4_v*>(base + (((2*j)   ^ (row & 7)) << 4)); \
      f32x4_v hi = *reinterpret_cast<const f32x4_v*>(base + (((2*j+1) ^ (row & 7)) << 4)); \
      af[m] = bf16x8_v{(__bf16)lo[0], (__bf16)lo[1], (__bf16)lo[2], (__bf16)lo[3], \
                       (__bf16)hi[0], (__bf16)hi[1], (__bf16)hi[2], (__bf16)hi[3]}; \
    }                                                                           \
    _Pragma("unroll")                                                           \
    for (int n = 0; n < 4; ++n) {                                               \
      int row = rB + n * 16;                                                    \
      int sl = (j + (row >> 1)) & 3;                                            \
      bf[n] = *reinterpret_cast<const bf16x8_v*>(Bb + row * 64 + sl * 16);      \
    }                                                                           \
    __builtin_amdgcn_s_setprio(1);                                              \
    _Pragma("unroll")                                                           \
    for (int m = 0; m < 4; ++m)                                                 \
      _Pragma("unroll")                                                         \
      for (int n = 0; n < 4; ++n)                                               \
        acc[m][n] = __builtin_amdgcn_mfma_f32_16x16x32_bf16(af[m], bf[n], acc[m][n], 0, 0, 0); \
    __builtin_amdgcn_s_setprio(0);                                              \
    __builtin_amdgcn_s_barrier();                                               \
    __builtin_amdgcn_sched_barrier(0);                                          \
  } while (0)

  // prologue: stage steps 0 and 1
  STAGE(0);
  STAGE(1);

  // main loop: steps 0..61 (stage T+2, wait stage T with 12 in flight)
  for (int t = 0; t < 62; ++t) {
    STAGE(t + 2);
    asm volatile("s_waitcnt vmcnt(12)" ::: "memory");
    STEP_BODY(t);
  }
  // tail steps
  asm volatile("s_waitcnt vmcnt(6)" ::: "memory");
  STEP_BODY(62);
  asm volatile("s_waitcnt vmcnt(0)" ::: "memory");
  STEP_BODY(63);

#undef STAGE
#undef STEP_BODY

  // ---- epilogue: z = acc + bias + cov*Wc; E_partial = sum_h tanh(z)*va[h]
  const int bb = m0 >> 11;            // batch (uniform per block)
  const int colg = lane & 15;
  const int rowg = lane >> 4;         // 0..3
  float bias_v[4], wc_v[4], va_v[4];
#pragma unroll
  for (int n = 0; n < 4; ++n) {
    int h = n0 + wn * 64 + n * 16 + colg;
    bias_v[n] = biasBH[bb * kH + h];
    wc_v[n] = Wc[h];
    va_v[n] = va[h];
  }
  const int s_tile = (m0 & (kS - 1));
  float rowsum[4][4];
#pragma unroll
  for (int m = 0; m < 4; ++m)
#pragma unroll
    for (int q = 0; q < 4; ++q) rowsum[m][q] = 0.f;

#pragma unroll
  for (int m = 0; m < 4; ++m) {
    int sbase = s_tile + wm * 64 + m * 16 + rowg * 4;
    float cov[4];
#pragma unroll
    for (int q = 0; q < 4; ++q) cov[q] = coverage[bb * kS + sbase + q];
#pragma unroll
    for (int n = 0; n < 4; ++n) {
#pragma unroll
      for (int q = 0; q < 4; ++q) {
        float z = acc[m][n][q] + bias_v[n] + cov[q] * wc_v[n];
        rowsum[m][q] += fast_tanh(z) * va_v[n];
      }
    }
  }
#pragma unroll
  for (int m = 0; m < 4; ++m) {
#pragma unroll
    for (int q = 0; q < 4; ++q) {
      float v = rowsum[m][q];
      v += __shfl_xor(v, 1);
      v += __shfl_xor(v, 2);
      v += __shfl_xor(v, 4);
      v += __shfl_xor(v, 8);
      if (colg == 0) {
        int s = s_tile + wm * 64 + m * 16 + rowg * 4 + q;
        atomicAdd(&E[bb * kS + s], v);
      }
    }
  }
}

// ---------------- softmax over S per (b); A and new_cov ---------------------
__global__ __launch_bounds__(256) void softmax_kernel(
    const float* __restrict__ E, const float* __restrict__ coverage,
    float* __restrict__ A, float* __restrict__ newcov) {
  int b = blockIdx.x;
  int tid = threadIdx.x;
  int wid = tid >> 6, lane = tid & 63;
  __shared__ float wred[4];
  float ev[8];
  float mx = -INFINITY;
#pragma unroll
  for (int i = 0; i < 8; ++i) {
    ev[i] = E[b * kS + tid + i * 256];
    mx = fmaxf(mx, ev[i]);
  }
  for (int m = 1; m < 64; m <<= 1) mx = fmaxf(mx, __shfl_xor(mx, m));
  if (lane == 0) wred[wid] = mx;
  __syncthreads();
  mx = fmaxf(fmaxf(wred[0], wred[1]), fmaxf(wred[2], wred[3]));
  __syncthreads();
  float sum = 0.f;
#pragma unroll
  for (int i = 0; i < 8; ++i) {
    ev[i] = __expf(ev[i] - mx);
    sum += ev[i];
  }
  for (int m = 1; m < 64; m <<= 1) sum += __shfl_xor(sum, m);
  if (lane == 0) wred[wid] = sum;
  __syncthreads();
  sum = wred[0] + wred[1] + wred[2] + wred[3];
  float inv = 1.f / sum;
#pragma unroll
  for (int i = 0; i < 8; ++i) {
    int s = tid + i * 256;
    float a = ev[i] * inv;
    A[b * kS + s] = a;
    newcov[b * kS + s] = coverage[b * kS + s] + a;
  }
}

// ---------------- context C[b] = sum_s A[b,s] * h_i[b,s,:] ------------------
__global__ __launch_bounds__(256) void context_kernel(
    const float* __restrict__ h_i, const float* __restrict__ A,
    float* __restrict__ C) {
  int b = blockIdx.x;
  int d = blockIdx.y * 1024 + threadIdx.x * 4;
  int s0 = blockIdx.z * 256;
  const float* hp = h_i + ((size_t)b * kS + s0) * kD + d;
  const float* ap = A + b * kS + s0;
  float4 acc = {0.f, 0.f, 0.f, 0.f};
  for (int s = 0; s < 256; ++s) {
    float a = ap[s];
    float4 v = *reinterpret_cast<const float4*>(hp + (size_t)s * kD);
    acc.x += a * v.x;
    acc.y += a * v.y;
    acc.z += a * v.z;
    acc.w += a * v.w;
  }
  atomicAdd(&C[b * kD + d + 0], acc.x);
  atomicAdd(&C[b * kD + d + 1], acc.y);
  atomicAdd(&C[b * kD + d + 2], acc.z);
  atomicAdd(&C[b * kD + d + 3], acc.w);
}

extern "C" void kernel_launch(void* const* d_in, const int* in_sizes, int n_in,
                              void* d_out, int out_size, void* d_ws, size_t ws_size,
                              hipStream_t stream) {
  const float* s_t      = (const float*)d_in[0];
  const float* h_i      = (const float*)d_in[1];
  const float* coverage = (const float*)d_in[2];
  const float* W_h      = (const float*)d_in[3];
  const float* b_h      = (const float*)d_in[4];
  const float* W_s      = (const float*)d_in[5];
  const float* b_s      = (const float*)d_in[6];
  const float* W_c      = (const float*)d_in[7];
  const float* v_a      = (const float*)d_in[8];
  // d_in[9] = b_a: softmax-shift-invariant and E is not an output -> unused.

  float* out = (float*)d_out;
  float* C      = out;                 // (kB, kD)
  float* A      = out + kB * kD;       // (kB, kS)
  float* newcov = A + kB * kS;         // (kB, kS)

  char* ws = (char*)d_ws;
  __bf16* Wh_bf  = (__bf16*)ws;                               // 4 MB (tiled)
  float* biasBH  = (float*)(ws + (4u << 20));                 // 256 KB
  float* E       = (float*)(ws + (4u << 20) + (256u << 10));  // 512 KB

  hipMemsetAsync(E, 0, (size_t)kB * kS * sizeof(float), stream);
  hipMemsetAsync(C, 0, (size_t)kB * kD * sizeof(float), stream);

  conv_wh_kernel<<<(kH * kD / 8) / 256, 256, 0, stream>>>(W_h, Wh_bf);
  prep_bias_kernel<<<(kB * kH) / 4, 256, 0, stream>>>(s_t, W_s, b_s, b_h, biasBH);

  gemm_score_kernel<<<8192, 256, 0, stream>>>(h_i, Wh_bf, biasBH, coverage, W_c, v_a, E);

  softmax_kernel<<<kB, 256, 0, stream>>>(E, coverage, A, newcov);

  dim3 gc(kB, kD / 1024, kS / 256);
  context_kernel<<<gc, 256, 0, stream>>>(h_i, A, C);
}

// Round 8
// 881.108 us; speedup vs baseline: 2.5416x; 1.5949x over previous
//
#include <hip/hip_runtime.h>
#include <hip/hip_bf16.h>

typedef __bf16 bf16x8_v __attribute__((ext_vector_type(8)));
typedef float  f32x4_v  __attribute__((ext_vector_type(4)));

static constexpr int kH = 1024;
static constexpr int kD = 2048;   // 2H
static constexpr int kB = 64;
static constexpr int kS = 2048;
static constexpr int kM = kB * kS;  // 131072 rows of the big GEMM

__device__ __forceinline__ void load_lds16(const void* g, void* l) {
  __builtin_amdgcn_global_load_lds(
      (const __attribute__((address_space(1))) unsigned int*)g,
      (__attribute__((address_space(3))) unsigned int*)l, 16, 0, 0);
}

__device__ __forceinline__ float fast_tanh(float x) {
  float e = __expf(2.0f * x);
  return 1.0f - 2.0f * __builtin_amdgcn_rcpf(e + 1.0f);
}

// ---- fp32 row-major [rows][2048] -> bf16 tiled ------------------------------
// Tile = 16 rows x 32 cols. Output: [row/16][kt=0..63][64 chunks of 16B].
// Chunk p: rr = p>>2 (row in tile), s = p&3 (slot). Slot s holds k-chunk
// c = s ^ ((rr>>1)&3)  -> GEMM reads slot j ^ ((row>>1)&3): XOR family,
// bank-quad per 8-lane group is a permutation (conflict-free, R5-proven).
__global__ __launch_bounds__(256) void conv_tile_kernel(const float* __restrict__ in,
                                                        __bf16* __restrict__ out) {
  size_t g = (size_t)blockIdx.x * 256 + threadIdx.x;
  int p = (int)(g & 63);
  size_t tile = g >> 6;
  int kt = (int)(tile & 63);
  size_t mt16 = tile >> 6;
  int rr = p >> 2, s = p & 3;
  int c = s ^ ((rr >> 1) & 3);
  const float* src = in + (mt16 * 16 + rr) * (size_t)kD + kt * 32 + c * 8;
  float4 v0 = reinterpret_cast<const float4*>(src)[0];
  float4 v1 = reinterpret_cast<const float4*>(src)[1];
  bf16x8_v o = {(__bf16)v0.x, (__bf16)v0.y, (__bf16)v0.z, (__bf16)v0.w,
                (__bf16)v1.x, (__bf16)v1.y, (__bf16)v1.z, (__bf16)v1.w};
  reinterpret_cast<bf16x8_v*>(out)[g] = o;
}

// ------------- biasBH[b][h] = s_t[b] . W_s[h] + b_s[h] + b_h[h] -------------
__global__ __launch_bounds__(256) void prep_bias_kernel(
    const float* __restrict__ s_t, const float* __restrict__ W_s,
    const float* __restrict__ b_s, const float* __restrict__ b_h,
    float* __restrict__ biasBH) {
  int wave = blockIdx.x * 4 + (threadIdx.x >> 6);  // 65536 outputs
  int lane = threadIdx.x & 63;
  int b = wave >> 10, h = wave & 1023;
  const float4* sp = reinterpret_cast<const float4*>(s_t + (size_t)b * kD);
  const float4* wp = reinterpret_cast<const float4*>(W_s + (size_t)h * kD);
  float acc = 0.f;
  for (int i = lane; i < kD / 4; i += 64) {
    float4 a = sp[i], w = wp[i];
    acc += a.x * w.x + a.y * w.y + a.z * w.z + a.w * w.w;
  }
  for (int m = 1; m < 64; m <<= 1) acc += __shfl_xor(acc, m);
  if (lane == 0) biasBH[wave] = acc + b_s[h] + b_h[h];
}

// ---------------- big GEMM + fused tanh/v_a epilogue -> E -------------------
// BM=256, BN=128, BK=32, 8 waves (4M x 2N; per-wave 64x64 output).
// Both operands pre-tiled bf16, staged 100% via global_load_lds (3 instr/wave
// per step), 2-deep LDS double-buffer (48 KB), counted vmcnt(3) -- never
// drained mid-loop. 2 barriers/step. No VALU conversion in the loop.
__global__ __launch_bounds__(512, 4) void gemm_score_kernel(
    const __bf16* __restrict__ Atl,     // tiled bf16 A for this chunk
    const __bf16* __restrict__ Btl,     // tiled bf16 W_h
    const float* __restrict__ biasBH,   // (kB, kH)
    const float* __restrict__ coverage, // (kB, kS)
    const float* __restrict__ Wc,       // (kH)
    const float* __restrict__ va,       // (kH)
    float* __restrict__ E,              // (kB, kS), pre-zeroed
    int mrow0) {                        // global row offset of this chunk
  const int bid = blockIdx.x;
  const int mtiles = gridDim.x >> 3;    // 256-row M-tiles in this chunk (mult of 8)
  const int mpx = mtiles >> 3;
  const int xcd = bid & 7;
  const int slot = bid >> 3;
  const int m_l = xcd * mpx + (slot >> 3);  // XCD-partitioned, n fastest
  const int nblk = slot & 7;
  const int n0 = nblk * 128;
  const int m0l = m_l * 256;            // chunk-local row base
  const int m0g = mrow0 + m0l;          // global row base

  const int tid = threadIdx.x;
  const int lane = tid & 63;
  const int wid = tid >> 6;             // 0..7
  const int wm = wid >> 1, wn = wid & 1;

  __shared__ char lds[49152];           // 2 x (A 16K + B 8K)

  f32x4_v acc[4][4];
#pragma unroll
  for (int m = 0; m < 4; ++m)
#pragma unroll
    for (int n = 0; n < 4; ++n) acc[m][n] = {0.f, 0.f, 0.f, 0.f};

  const int rA = wm * 64 + (lane & 15);
  const int rB = wn * 64 + (lane & 15);
  const int slot16 = (((lane >> 4) ^ ((lane >> 1) & 3)) << 4);

  const size_t mt16b = (size_t)(m0l >> 4);      // first 16-row A tile
  const size_t nt16b = (size_t)(nblk * 8);      // first 16-row B tile

  // per-wave staging: A sub-tiles wid*2, wid*2+1 ; B sub-tile wid
  const __bf16* Asrc0 = Atl + ((mt16b + wid * 2) * 64) * 512 + lane * 8;
  const __bf16* Asrc1 = Atl + ((mt16b + wid * 2 + 1) * 64) * 512 + lane * 8;
  const __bf16* Bsrc  = Btl + ((nt16b + wid) * 64) * 512 + lane * 8;
  char* Adst0 = lds + wid * 2048;
  char* Adst1 = lds + wid * 2048 + 1024;
  char* Bdst  = lds + 16384 + wid * 1024;

#define STAGE(T)                                                  \
  do {                                                            \
    int boff = ((T) & 1) * 24576;                                 \
    load_lds16(Asrc0 + (size_t)(T) * 512, Adst0 + boff);          \
    load_lds16(Asrc1 + (size_t)(T) * 512, Adst1 + boff);          \
    load_lds16(Bsrc + (size_t)(T) * 512, Bdst + boff);            \
  } while (0)

  STAGE(0);
  STAGE(1);

#pragma unroll 2
  for (int t = 0; t < 64; ++t) {
    if (t < 63) asm volatile("s_waitcnt vmcnt(3)" ::: "memory");
    else        asm volatile("s_waitcnt vmcnt(0)" ::: "memory");
    __builtin_amdgcn_s_barrier();
    asm volatile("" ::: "memory");

    const char* Ab = lds + (t & 1) * 24576;
    const char* Bb = Ab + 16384;
    bf16x8_v a[4], b[4];
#pragma unroll
    for (int m = 0; m < 4; ++m)
      a[m] = *reinterpret_cast<const bf16x8_v*>(Ab + (rA + m * 16) * 64 + slot16);
#pragma unroll
    for (int n = 0; n < 4; ++n)
      b[n] = *reinterpret_cast<const bf16x8_v*>(Bb + (rB + n * 16) * 64 + slot16);
    __builtin_amdgcn_s_setprio(1);
#pragma unroll
    for (int m = 0; m < 4; ++m)
#pragma unroll
      for (int n = 0; n < 4; ++n)
        acc[m][n] = __builtin_amdgcn_mfma_f32_16x16x32_bf16(a[m], b[n], acc[m][n], 0, 0, 0);
    __builtin_amdgcn_s_setprio(0);

    asm volatile("s_waitcnt lgkmcnt(0)" ::: "memory");
    __builtin_amdgcn_s_barrier();
    asm volatile("" ::: "memory");
    if (t + 2 < 64) STAGE(t + 2);
  }
#undef STAGE

  // ---- epilogue: z = acc + bias + cov*Wc; E_partial = sum_h tanh(z)*va[h]
  const int bb = m0g >> 11;             // batch (256-row tile within one batch)
  const int colg = lane & 15;
  const int rowg = lane >> 4;           // 0..3
  float bias_v[4], wc_v[4], va_v[4];
#pragma unroll
  for (int n = 0; n < 4; ++n) {
    int h = n0 + wn * 64 + n * 16 + colg;
    bias_v[n] = biasBH[bb * kH + h];
    wc_v[n] = Wc[h];
    va_v[n] = va[h];
  }
  const int s_tile = (m0g & (kS - 1));
  float rowsum[4][4];
#pragma unroll
  for (int m = 0; m < 4; ++m)
#pragma unroll
    for (int q = 0; q < 4; ++q) rowsum[m][q] = 0.f;

#pragma unroll
  for (int m = 0; m < 4; ++m) {
    int sbase = s_tile + wm * 64 + m * 16 + rowg * 4;
    float cov[4];
#pragma unroll
    for (int q = 0; q < 4; ++q) cov[q] = coverage[bb * kS + sbase + q];
#pragma unroll
    for (int n = 0; n < 4; ++n) {
#pragma unroll
      for (int q = 0; q < 4; ++q) {
        float z = acc[m][n][q] + bias_v[n] + cov[q] * wc_v[n];
        rowsum[m][q] += fast_tanh(z) * va_v[n];
      }
    }
  }
#pragma unroll
  for (int m = 0; m < 4; ++m) {
#pragma unroll
    for (int q = 0; q < 4; ++q) {
      float v = rowsum[m][q];
      v += __shfl_xor(v, 1);
      v += __shfl_xor(v, 2);
      v += __shfl_xor(v, 4);
      v += __shfl_xor(v, 8);
      if (colg == 0) {
        int s = s_tile + wm * 64 + m * 16 + rowg * 4 + q;
        atomicAdd(&E[bb * kS + s], v);
      }
    }
  }
}

// ---------------- softmax over S per (b); A and new_cov ---------------------
__global__ __launch_bounds__(256) void softmax_kernel(
    const float* __restrict__ E, const float* __restrict__ coverage,
    float* __restrict__ A, float* __restrict__ newcov) {
  int b = blockIdx.x;
  int tid = threadIdx.x;
  int wid = tid >> 6, lane = tid & 63;
  __shared__ float wred[4];
  float ev[8];
  float mx = -INFINITY;
#pragma unroll
  for (int i = 0; i < 8; ++i) {
    ev[i] = E[b * kS + tid + i * 256];
    mx = fmaxf(mx, ev[i]);
  }
  for (int m = 1; m < 64; m <<= 1) mx = fmaxf(mx, __shfl_xor(mx, m));
  if (lane == 0) wred[wid] = mx;
  __syncthreads();
  mx = fmaxf(fmaxf(wred[0], wred[1]), fmaxf(wred[2], wred[3]));
  __syncthreads();
  float sum = 0.f;
#pragma unroll
  for (int i = 0; i < 8; ++i) {
    ev[i] = __expf(ev[i] - mx);
    sum += ev[i];
  }
  for (int m = 1; m < 64; m <<= 1) sum += __shfl_xor(sum, m);
  if (lane == 0) wred[wid] = sum;
  __syncthreads();
  sum = wred[0] + wred[1] + wred[2] + wred[3];
  float inv = 1.f / sum;
#pragma unroll
  for (int i = 0; i < 8; ++i) {
    int s = tid + i * 256;
    float a = ev[i] * inv;
    A[b * kS + s] = a;
    newcov[b * kS + s] = coverage[b * kS + s] + a;
  }
}

// ------- context from TILED bf16 h_i (only valid when whole h_i tiled) ------
__global__ __launch_bounds__(256) void context_bf16_kernel(
    const __bf16* __restrict__ Atl, const float* __restrict__ A,
    float* __restrict__ C) {
  int b = blockIdx.x;
  int s0 = blockIdx.y * 256;
  int t = threadIdx.x;
  int kt = t >> 2, c = t & 3;
  float acc[8];
#pragma unroll
  for (int i = 0; i < 8; ++i) acc[i] = 0.f;
  for (int si = 0; si < 256; ++si) {
    int s = s0 + si;
    float a = A[b * kS + s];
    size_t mt16 = (size_t)b * 128 + (s >> 4);
    int sl = c ^ (((s >> 1)) & 3);
    size_t idx = (mt16 * 64 + kt) * 512 + (size_t)(((s & 15) * 4 + sl)) * 8;
    bf16x8_v v = *reinterpret_cast<const bf16x8_v*>(Atl + idx);
#pragma unroll
    for (int i = 0; i < 8; ++i) acc[i] += a * (float)v[i];
  }
  int d = kt * 32 + c * 8;
#pragma unroll
  for (int i = 0; i < 8; ++i) atomicAdd(&C[b * kD + d + i], acc[i]);
}

// ---------------- context from fp32 h_i (chunked fallback) ------------------
__global__ __launch_bounds__(256) void context_kernel(
    const float* __restrict__ h_i, const float* __restrict__ A,
    float* __restrict__ C) {
  int b = blockIdx.x;
  int d = blockIdx.y * 1024 + threadIdx.x * 4;
  int s0 = blockIdx.z * 256;
  const float* hp = h_i + ((size_t)b * kS + s0) * kD + d;
  const float* ap = A + b * kS + s0;
  float4 acc = {0.f, 0.f, 0.f, 0.f};
  for (int s = 0; s < 256; ++s) {
    float a = ap[s];
    float4 v = *reinterpret_cast<const float4*>(hp + (size_t)s * kD);
    acc.x += a * v.x;
    acc.y += a * v.y;
    acc.z += a * v.z;
    acc.w += a * v.w;
  }
  atomicAdd(&C[b * kD + d + 0], acc.x);
  atomicAdd(&C[b * kD + d + 1], acc.y);
  atomicAdd(&C[b * kD + d + 2], acc.z);
  atomicAdd(&C[b * kD + d + 3], acc.w);
}

extern "C" void kernel_launch(void* const* d_in, const int* in_sizes, int n_in,
                              void* d_out, int out_size, void* d_ws, size_t ws_size,
                              hipStream_t stream) {
  const float* s_t      = (const float*)d_in[0];
  const float* h_i      = (const float*)d_in[1];
  const float* coverage = (const float*)d_in[2];
  const float* W_h      = (const float*)d_in[3];
  const float* b_h      = (const float*)d_in[4];
  const float* W_s      = (const float*)d_in[5];
  const float* b_s      = (const float*)d_in[6];
  const float* W_c      = (const float*)d_in[7];
  const float* v_a      = (const float*)d_in[8];
  // d_in[9] = b_a: softmax-shift-invariant and E is not an output -> unused.

  float* out = (float*)d_out;
  float* C      = out;                 // (kB, kD)
  float* A      = out + kB * kD;       // (kB, kS)
  float* newcov = A + kB * kS;         // (kB, kS)

  // ---- adaptive chunking of the tiled-bf16 h_i buffer by ws_size
  size_t reserved = 8u << 20;          // Wtl 4MB + biasBH + E + slack
  size_t avail = ws_size > reserved ? ws_size - reserved : 0;
  int chunk_rows = 2048;
  for (long cr = (long)kM; cr >= 2048; cr >>= 1) {
    if ((size_t)cr * kD * 2 <= avail) { chunk_rows = (int)cr; break; }
  }
  int nchunks = kM / chunk_rows;

  char* ws = (char*)d_ws;
  __bf16* Atl   = (__bf16*)ws;                                  // chunked tiled A
  size_t atl_bytes = (size_t)chunk_rows * kD * 2;
  __bf16* Wtl   = (__bf16*)(ws + atl_bytes);                    // 4 MB tiled W_h
  float* biasBH = (float*)(ws + atl_bytes + (4u << 20));        // 256 KB
  float* E      = (float*)(ws + atl_bytes + (4u << 20) + (256u << 10));  // 512 KB

  hipMemsetAsync(E, 0, (size_t)kB * kS * sizeof(float), stream);
  hipMemsetAsync(C, 0, (size_t)kB * kD * sizeof(float), stream);

  conv_tile_kernel<<<kH, 256, 0, stream>>>(W_h, Wtl);
  prep_bias_kernel<<<(kB * kH) / 4, 256, 0, stream>>>(s_t, W_s, b_s, b_h, biasBH);

  for (int ch = 0; ch < nchunks; ++ch) {
    int mrow0 = ch * chunk_rows;
    conv_tile_kernel<<<chunk_rows, 256, 0, stream>>>(h_i + (size_t)mrow0 * kD, Atl);
    int mtiles = chunk_rows / 256;
    gemm_score_kernel<<<mtiles * 8, 512, 0, stream>>>(Atl, Wtl, biasBH, coverage,
                                                      W_c, v_a, E, mrow0);
  }

  softmax_kernel<<<kB, 256, 0, stream>>>(E, coverage, A, newcov);

  if (nchunks == 1) {
    dim3 gc(kB, kS / 256, 1);
    context_bf16_kernel<<<gc, 256, 0, stream>>>(Atl, A, C);
  } else {
    dim3 gc(kB, kD / 1024, kS / 256);
    context_kernel<<<gc, 256, 0, stream>>>(h_i, A, C);
  }
}